// Round 17
// baseline (326.487 us; speedup 1.0000x reference)
//
#include <hip/hip_runtime.h>
#include <hip/hip_bf16.h>
#include <math.h>

#define N_NODES 100000
#define N_EDGES 1600000
#define NF 128
#define NC 40

// bucketed CSR build
#define NB 256                 // buckets
#define NPB 391                // nodes per bucket (ceil(100000/256))
#define CAP 8192               // slab capacity (mean 6250, +24 sigma)
#define PART_BLOCKS 512
#define PART_E ((N_EDGES + PART_BLOCKS - 1) / PART_BLOCKS)   // 3125

// weight arena: 5 128x128 + 1 padded 48x128 (W_post, rows 40-47 zero)
#define WB_ELEMS (5 * 16384 + 48 * 128)

typedef __attribute__((ext_vector_type(8))) short short8v;   // 8 bf16 = 4 VGPRs
typedef __attribute__((ext_vector_type(4))) float f32x4;
typedef __attribute__((ext_vector_type(2))) float f32x2;
typedef unsigned short ushort_t;

__device__ inline float bflo(unsigned v) { union { unsigned u; float f; } x; x.u = v << 16; return x.f; }
__device__ inline float bfhi(unsigned v) { union { unsigned u; float f; } x; x.u = v & 0xffff0000u; return x.f; }
__device__ inline ushort_t f2bf(float f) {
    __hip_bfloat16 h = __float2bfloat16(f);
    return __builtin_bit_cast(ushort_t, h);
}

// decode 8 fp8 (uint2) -> accumulate into 4 f32x2 (v_cvt_pk + v_pk_add_f32)
__device__ inline void acc_fp8x8p(uint2 v, f32x2& a0, f32x2& a1, f32x2& a2, f32x2& a3) {
    a0 += __builtin_amdgcn_cvt_pk_f32_fp8((int)v.x, false);
    a1 += __builtin_amdgcn_cvt_pk_f32_fp8((int)v.x, true);
    a2 += __builtin_amdgcn_cvt_pk_f32_fp8((int)v.y, false);
    a3 += __builtin_amdgcn_cvt_pk_f32_fp8((int)v.y, true);
}

__device__ inline short8v cvt_f32x8_bf16(float4 f0, float4 f1) {
    short8v v;
    v[0] = (short)f2bf(f0.x); v[1] = (short)f2bf(f0.y);
    v[2] = (short)f2bf(f0.z); v[3] = (short)f2bf(f0.w);
    v[4] = (short)f2bf(f1.x); v[5] = (short)f2bf(f1.y);
    v[6] = (short)f2bf(f1.z); v[7] = (short)f2bf(f1.w);
    return v;
}

// ---------------- bucketed CSR build + fused weight cast ----------------
// blocks 0..511: LDS histogram + slab partition (each (block,bucket) output
// stream contiguous -> no cross-XCD line ping-pong). block 512: cast the 5
// 128x128 weights + padded 48x128 W_post to bf16. Both roles are ~16-VGPR
// trivial kernels -> safe to co-compile (r16 lesson: never merge a fat GEMM
// with thin roles — shared regalloc pinned VGPR=64 and spilled the GEMM).

__global__ __launch_bounds__(256) void k_part2(const int* __restrict__ src,
                                               const int* __restrict__ dst,
                                               unsigned* __restrict__ bcur,
                                               uint2* __restrict__ pairs,
                                               const float* __restrict__ w0,
                                               const float* __restrict__ w1,
                                               const float* __restrict__ w2,
                                               const float* __restrict__ w3,
                                               const float* __restrict__ w4,
                                               const float* __restrict__ wp,
                                               ushort_t* __restrict__ wbout) {
    __shared__ unsigned cnt[NB];
    __shared__ unsigned curs[NB];
    const int t = threadIdx.x;
    if (blockIdx.x >= PART_BLOCKS) {
        for (int i = t; i < WB_ELEMS; i += 256) {
            if (i < 5 * 16384) {
                int m = i >> 14, j = i & 16383;
                const float* s = (m == 0) ? w0 : (m == 1) ? w1 : (m == 2) ? w2 : (m == 3) ? w3 : w4;
                wbout[i] = f2bf(s[j]);
            } else {
                int j = i - 5 * 16384;
                int row = j >> 7, col = j & 127;
                wbout[i] = (row < NC) ? f2bf(wp[row * NF + col]) : (ushort_t)0;
            }
        }
        return;
    }
    cnt[t] = 0;
    __syncthreads();
    const int e0 = blockIdx.x * PART_E;
    int e1 = e0 + PART_E; if (e1 > N_EDGES) e1 = N_EDGES;
    for (int e = e0 + t; e < e1; e += 256)
        atomicAdd(&cnt[dst[e] / NPB], 1u);
    __syncthreads();
    unsigned c = cnt[t];
    curs[t] = c ? atomicAdd(&bcur[t], c) : 0u;   // reserve slab range once
    __syncthreads();
    for (int e = e0 + t; e < e1; e += 256) {
        int d = dst[e];
        int s = src[e];
        int b = d / NPB;
        unsigned p = atomicAdd(&curs[b], 1u);
        if (p < CAP) pairs[(size_t)b * CAP + p] = make_uint2((unsigned)d, (unsigned)s);
    }
}

__global__ void k_bscan(const unsigned* __restrict__ bcur,
                        unsigned* __restrict__ bbase,
                        unsigned* __restrict__ rowptr) {
    __shared__ unsigned s[NB];
    const int t = threadIdx.x;
    unsigned v = bcur[t];
    s[t] = v; __syncthreads();
    for (int off = 1; off < NB; off <<= 1) {
        unsigned u = (t >= off) ? s[t - off] : 0;
        __syncthreads();
        s[t] += u;
        __syncthreads();
    }
    bbase[t] = s[t] - v;
    if (t == NB - 1) rowptr[N_NODES] = s[NB - 1];   // == N_EDGES
}

__global__ __launch_bounds__(256) void k_bucket(const uint2* __restrict__ pairs,
                                                const unsigned* __restrict__ bcur,
                                                const unsigned* __restrict__ bbase,
                                                unsigned* __restrict__ rowptr,
                                                unsigned* __restrict__ srcs) {
    __shared__ unsigned s[512];
    const int t = threadIdx.x;
    const int b = blockIdx.x;
    unsigned cnt = bcur[b]; if (cnt > CAP) cnt = CAP;
    const unsigned base = bbase[b];
    const int n0 = b * NPB;
    int nn = N_NODES - n0; if (nn > NPB) nn = NPB;
    const uint2* pp = pairs + (size_t)b * CAP;

    s[t] = 0; s[t + 256] = 0;
    __syncthreads();
    for (unsigned i = t; i < cnt; i += 256)
        atomicAdd(&s[pp[i].x - n0], 1u);
    __syncthreads();
    unsigned d0 = s[t], d1 = s[t + 256];
    for (int off = 1; off < 512; off <<= 1) {       // inclusive scan, 512 wide
        unsigned u0 = (t >= off) ? s[t - off] : 0;
        unsigned u1 = (t + 256 >= off) ? s[t + 256 - off] : 0;
        __syncthreads();
        s[t] += u0; s[t + 256] += u1;
        __syncthreads();
    }
    unsigned ex0 = base + s[t] - d0;                // global exclusive offsets
    unsigned ex1 = base + s[t + 256] - d1;
    __syncthreads();
    s[t] = ex0; s[t + 256] = ex1;                   // become scatter cursors
    if (t < nn) rowptr[n0 + t] = ex0;
    if (t + 256 < nn) rowptr[n0 + t + 256] = ex1;
    __syncthreads();
    for (unsigned i = t; i < cnt; i += 256) {
        uint2 e = pp[i];
        unsigned p = atomicAdd(&s[e.x - n0], 1u);
        srcs[p] = e.y;
    }
}

// ---------------- mean aggregation over fp8 shadow copy ----------------
// One wave per node; 4 edge-slots x 16 lanes; MLP 4-deep main loop; f32x2
// packed accumulate. At its L2-miss throughput floor (~81MB @ ~1.8TB/s).

__global__ __launch_bounds__(256) void k_aggregate8(const uint2* __restrict__ h64,
                                                    const unsigned* __restrict__ rowptr,
                                                    const unsigned* __restrict__ srcs,
                                                    ushort_t* __restrict__ agg) {
    int wave = threadIdx.x >> 6;
    int lane = threadIdx.x & 63;
    int node = blockIdx.x * 4 + wave;
    if (node >= N_NODES) return;
    const int slot = lane >> 4;
    const int d = lane & 15;
    unsigned beg = rowptr[node], end = rowptr[node + 1];
    f32x2 a0 = {0.f, 0.f}, a1 = {0.f, 0.f}, a2 = {0.f, 0.f}, a3 = {0.f, 0.f};
    unsigned i = beg;
    for (; i + 16 <= end; i += 16) {
        unsigned s0 = srcs[i + slot];
        unsigned s1 = srcs[i + 4 + slot];
        unsigned s2 = srcs[i + 8 + slot];
        unsigned s3 = srcs[i + 12 + slot];
        uint2 v0 = h64[(size_t)s0 * 16 + d];
        uint2 v1 = h64[(size_t)s1 * 16 + d];
        uint2 v2 = h64[(size_t)s2 * 16 + d];
        uint2 v3 = h64[(size_t)s3 * 16 + d];
        acc_fp8x8p(v0, a0, a1, a2, a3);
        acc_fp8x8p(v1, a0, a1, a2, a3);
        acc_fp8x8p(v2, a0, a1, a2, a3);
        acc_fp8x8p(v3, a0, a1, a2, a3);
    }
    if (i + 8 <= end) {
        unsigned s0 = srcs[i + slot];
        unsigned s1 = srcs[i + 4 + slot];
        uint2 v0 = h64[(size_t)s0 * 16 + d];
        uint2 v1 = h64[(size_t)s1 * 16 + d];
        acc_fp8x8p(v0, a0, a1, a2, a3);
        acc_fp8x8p(v1, a0, a1, a2, a3);
        i += 8;
    }
    if (i + 4 <= end) {
        unsigned s0 = srcs[i + slot];
        uint2 v0 = h64[(size_t)s0 * 16 + d];
        acc_fp8x8p(v0, a0, a1, a2, a3);
        i += 4;
    }
    if (i + slot < end) {
        unsigned s0 = srcs[i + slot];
        uint2 v0 = h64[(size_t)s0 * 16 + d];
        acc_fp8x8p(v0, a0, a1, a2, a3);
    }
    float r[8] = {a0.x, a0.y, a1.x, a1.y, a2.x, a2.y, a3.x, a3.y};
#pragma unroll
    for (int j = 0; j < 8; ++j) {
        r[j] += __shfl_xor(r[j], 16, 64);
        r[j] += __shfl_xor(r[j], 32, 64);
    }
    if (slot == 0) {
        float sc = 1.f / fmaxf((float)(end - beg), 1.f);
        uint4 o;
        o.x = ((unsigned)f2bf(r[1] * sc) << 16) | (unsigned)f2bf(r[0] * sc);
        o.y = ((unsigned)f2bf(r[3] * sc) << 16) | (unsigned)f2bf(r[2] * sc);
        o.z = ((unsigned)f2bf(r[5] * sc) << 16) | (unsigned)f2bf(r[4] * sc);
        o.w = ((unsigned)f2bf(r[7] * sc) << 16) | (unsigned)f2bf(r[6] * sc);
        ((uint4*)(agg + (size_t)node * NF))[d] = o;
    }
}

// ---------------- 2-tile pipelined MFMA GEMM (pre & conv0) ----------------
// r15-proven. Grid 391 x 512thr; block owns tiles 2b, 2b+1. Weights staged
// ONCE in swizzled LDS; separate 16K wb region so weights stay live -> tile1
// A-loads issue before tile0 writeback. Writeback: half-tile x 2 passes;
// threads 0-255 store bf16 64B segs, 256-511 convert+store fp8 32B segs.

template <int SRC_F32, int HAS2>
__global__ __launch_bounds__(512, 4) void k_gemm2(const void* __restrict__ A1v,
                                                  const ushort_t* __restrict__ A2,
                                                  const ushort_t* __restrict__ W1,
                                                  const ushort_t* __restrict__ W2,
                                                  const float* __restrict__ bias,
                                                  ushort_t* __restrict__ out,
                                                  unsigned char* __restrict__ out8) {
    constexpr int WLDS = HAS2 ? 65536 : 32768;
    __shared__ char ldsc[WLDS + 16384];
    char* wbl = ldsc + WLDS;
    const int t = threadIdx.x;
    const int lane = t & 63;
    const int wv = t >> 6;
    const int lr = lane & 15;
    const int kg = lane >> 4;
    const int tile0 = blockIdx.x * 2;

    // ---- stage weights into swizzled LDS (once per block) ----
    {
        const int n1 = 128 * 16;
        for (int c = t; c < n1; c += 512) {
            int row = c >> 4, s16 = c & 15;
            uint4 v = ((const uint4*)(W1 + (size_t)row * NF))[s16];
            *(uint4*)(&ldsc[row * 256 + ((s16 * 16) ^ ((row & 7) << 4))]) = v;
        }
        if (HAS2) {
            for (int c = t; c < n1; c += 512) {
                int row = c >> 4, s16 = c & 15;
                uint4 v = ((const uint4*)(W2 + (size_t)row * NF))[s16];
                int lrow = 128 + row;
                *(uint4*)(&ldsc[lrow * 256 + ((s16 * 16) ^ ((lrow & 7) << 4))]) = v;
            }
        }
    }

    float bv[8];
#pragma unroll
    for (int ct = 0; ct < 8; ++ct) bv[ct] = bias[ct * 16 + lr];

    auto do_mfma = [&](short8v (&a1)[4], short8v (&a2)[4], f32x4 (&ac)[8]) {
#pragma unroll
        for (int ct = 0; ct < 8; ++ct) ac[ct] = (f32x4){0.f, 0.f, 0.f, 0.f};
#pragma unroll
        for (int ct = 0; ct < 8; ++ct) {
#pragma unroll
            for (int ks = 0; ks < 4; ++ks) {
                int row = ct * 16 + lr;
                short8v b = *(const short8v*)(&ldsc[row * 256 + ((ks * 64 + kg * 16) ^ ((row & 7) << 4))]);
                ac[ct] = __builtin_amdgcn_mfma_f32_16x16x32_bf16(a1[ks], b, ac[ct], 0, 0, 0);
            }
            if (HAS2) {
#pragma unroll
                for (int ks = 0; ks < 4; ++ks) {
                    int row = 128 + ct * 16 + lr;
                    short8v b = *(const short8v*)(&ldsc[row * 256 + ((ks * 64 + kg * 16) ^ ((row & 7) << 4))]);
                    ac[ct] = __builtin_amdgcn_mfma_f32_16x16x32_bf16(a2[ks], b, ac[ct], 0, 0, 0);
                }
            }
        }
    };

    auto writeback = [&](int tile, f32x4 (&ac)[8]) {
#pragma unroll
        for (int pass = 0; pass < 2; ++pass) {
            __syncthreads();   // wb region free (prior readers done)
            if ((wv >> 2) == pass) {
#pragma unroll
                for (int ct = 0; ct < 8; ++ct) {
#pragma unroll
                    for (int r = 0; r < 4; ++r) {
                        float v = ac[ct][r] + bv[ct];
                        if (!SRC_F32) v = fmaxf(v, 0.f);   // relu on convs only
                        int row = (wv & 3) * 16 + kg * 4 + r;
                        int boff = (ct * 32 + lr * 2) ^ ((row & 7) << 4);
                        *(ushort_t*)(&wbl[row * 256 + boff]) = f2bf(v);
                    }
                }
            }
            __syncthreads();
            const int u = t & 255;
            const int row = u >> 2, seg = u & 3;
            const int grow = tile * 128 + pass * 64 + row;
            uint4 vv[4];
#pragma unroll
            for (int k = 0; k < 4; ++k) {
                int s16 = seg * 4 + k;
                vv[k] = *(const uint4*)(&wbl[row * 256 + ((s16 * 16) ^ ((row & 7) << 4))]);
            }
            if (grow < N_NODES) {
                if (t < 256) {
                    uint4* op = (uint4*)(out + (size_t)grow * NF);
#pragma unroll
                    for (int k = 0; k < 4; ++k) op[seg * 4 + k] = vv[k];
                } else {
                    const unsigned* uu = (const unsigned*)vv;
                    unsigned f8[8];
#pragma unroll
                    for (int k = 0; k < 8; ++k) {
                        int p0 = __builtin_amdgcn_cvt_pk_fp8_f32(bflo(uu[2 * k]), bfhi(uu[2 * k]), 0, false);
                        f8[k] = (unsigned)__builtin_amdgcn_cvt_pk_fp8_f32(bflo(uu[2 * k + 1]), bfhi(uu[2 * k + 1]), p0, true);
                    }
                    uint4* o8 = (uint4*)(out8 + (size_t)grow * NF + seg * 32);
                    o8[0] = make_uint4(f8[0], f8[1], f8[2], f8[3]);
                    o8[1] = make_uint4(f8[4], f8[5], f8[6], f8[7]);
                }
            }
        }
    };

    // ---- tile0 A loads ----
    short8v afA1[4], afA2[4];
    {
        int arow = tile0 * 128 + wv * 16 + lr;
        if (arow >= N_NODES) arow = N_NODES - 1;
        if (SRC_F32) {
            const float* x = (const float*)A1v;
#pragma unroll
            for (int ks = 0; ks < 4; ++ks) {
                const float4* xp = (const float4*)(x + (size_t)arow * NF + ks * 32 + kg * 8);
                afA1[ks] = cvt_f32x8_bf16(xp[0], xp[1]);
            }
        } else {
            const short8v* p = (const short8v*)((const ushort_t*)A1v + (size_t)arow * NF + kg * 8);
#pragma unroll
            for (int ks = 0; ks < 4; ++ks) afA1[ks] = p[ks * 4];
        }
        if (HAS2) {
            const short8v* p2 = (const short8v*)(A2 + (size_t)arow * NF + kg * 8);
#pragma unroll
            for (int ks = 0; ks < 4; ++ks) afA2[ks] = p2[ks * 4];
        }
    }
    __syncthreads();   // weights staged

    f32x4 acc[8];
    do_mfma(afA1, afA2, acc);

    // ---- prefetch tile1 A (issued before tile0 writeback; latency hides) ----
    short8v afB1[4], afB2[4];
    float4 rawB[8];
    {
        int arow = (tile0 + 1) * 128 + wv * 16 + lr;
        if (arow >= N_NODES) arow = N_NODES - 1;
        if (SRC_F32) {
            const float* x = (const float*)A1v;
#pragma unroll
            for (int ks = 0; ks < 4; ++ks) {
                const float4* xp = (const float4*)(x + (size_t)arow * NF + ks * 32 + kg * 8);
                rawB[2 * ks] = xp[0];
                rawB[2 * ks + 1] = xp[1];
            }
        } else {
            const short8v* p = (const short8v*)((const ushort_t*)A1v + (size_t)arow * NF + kg * 8);
#pragma unroll
            for (int ks = 0; ks < 4; ++ks) afB1[ks] = p[ks * 4];
        }
        if (HAS2) {
            const short8v* p2 = (const short8v*)(A2 + (size_t)arow * NF + kg * 8);
#pragma unroll
            for (int ks = 0; ks < 4; ++ks) afB2[ks] = p2[ks * 4];
        }
    }

    writeback(tile0, acc);

    if (SRC_F32) {
#pragma unroll
        for (int ks = 0; ks < 4; ++ks)
            afB1[ks] = cvt_f32x8_bf16(rawB[2 * ks], rawB[2 * ks + 1]);
    }

    do_mfma(afB1, afB2, acc);
    writeback(tile0 + 1, acc);
}

// ---------------- conv1 GEMM (single-tile) + fused post + log-softmax ----------------
// r14-proven path: weights+Wpost in LDS; h2 tile -> Wl LDS region after
// barrier; 3 MFMAs vs padded W_post; 16-lane shuffle softmax; f32 out.

__global__ __launch_bounds__(512) void k_gemm_post(const ushort_t* __restrict__ A1,
                                                   const ushort_t* __restrict__ A2,
                                                   const ushort_t* __restrict__ W1,
                                                   const ushort_t* __restrict__ W2,
                                                   const float* __restrict__ bias,
                                                   const ushort_t* __restrict__ Wp,
                                                   const float* __restrict__ bp,
                                                   float* __restrict__ outf) {
    __shared__ char ldsc[65536 + 12288];
    const int t = threadIdx.x;
    const int lane = t & 63;
    const int wv = t >> 6;
    const int r0 = blockIdx.x * 128 + wv * 16;
    const int lr = lane & 15;
    const int kg = lane >> 4;

    // ---- stage weights into swizzled LDS ----
    {
        const int nchunk1 = 128 * 16;
        for (int c = t; c < nchunk1; c += 512) {
            int row = c >> 4, s16 = c & 15;
            uint4 v = ((const uint4*)(W1 + (size_t)row * NF))[s16];
            *(uint4*)(&ldsc[row * 256 + ((s16 * 16) ^ ((row & 7) << 4))]) = v;
        }
        for (int c = t; c < nchunk1; c += 512) {
            int row = c >> 4, s16 = c & 15;
            uint4 v = ((const uint4*)(W2 + (size_t)row * NF))[s16];
            int lrow = 128 + row;
            *(uint4*)(&ldsc[lrow * 256 + ((s16 * 16) ^ ((lrow & 7) << 4))]) = v;
        }
        for (int c = t; c < 48 * 16; c += 512) {
            int row = c >> 4, s16 = c & 15;
            uint4 v = ((const uint4*)(Wp + (size_t)row * NF))[s16];
            int lrow = 256 + row;
            *(uint4*)(&ldsc[lrow * 256 + ((s16 * 16) ^ ((lrow & 7) << 4))]) = v;
        }
    }

    int arow = r0 + lr;
    if (arow >= N_NODES) arow = N_NODES - 1;   // clamp; stores guarded
    short8v af1[4], af2[4];
    {
        const short8v* a1p = (const short8v*)(A1 + (size_t)arow * NF + kg * 8);
#pragma unroll
        for (int ks = 0; ks < 4; ++ks) af1[ks] = a1p[ks * 4];
        const short8v* a2p = (const short8v*)(A2 + (size_t)arow * NF + kg * 8);
#pragma unroll
        for (int ks = 0; ks < 4; ++ks) af2[ks] = a2p[ks * 4];
    }
    __syncthreads();

    f32x4 acc[8];
#pragma unroll
    for (int ct = 0; ct < 8; ++ct) acc[ct] = (f32x4){0.f, 0.f, 0.f, 0.f};
#pragma unroll
    for (int ct = 0; ct < 8; ++ct) {
#pragma unroll
        for (int ks = 0; ks < 4; ++ks) {
            int row = ct * 16 + lr;
            short8v b = *(const short8v*)(&ldsc[row * 256 + ((ks * 64 + kg * 16) ^ ((row & 7) << 4))]);
            acc[ct] = __builtin_amdgcn_mfma_f32_16x16x32_bf16(af1[ks], b, acc[ct], 0, 0, 0);
        }
#pragma unroll
        for (int ks = 0; ks < 4; ++ks) {
            int row = 128 + ct * 16 + lr;
            short8v b = *(const short8v*)(&ldsc[row * 256 + ((ks * 64 + kg * 16) ^ ((row & 7) << 4))]);
            acc[ct] = __builtin_amdgcn_mfma_f32_16x16x32_bf16(af2[ks], b, acc[ct], 0, 0, 0);
        }
    }

    // all waves must finish reading Wl region before it becomes the h2 tile
    __syncthreads();
#pragma unroll
    for (int ct = 0; ct < 8; ++ct) {
        float bvv = bias[ct * 16 + lr];
#pragma unroll
        for (int r = 0; r < 4; ++r) {
            float v = fmaxf(acc[ct][r] + bvv, 0.f);
            int row = wv * 16 + kg * 4 + r;
            int boff = (ct * 32 + lr * 2) ^ ((row & 7) << 4);
            *(ushort_t*)(&ldsc[row * 256 + boff]) = f2bf(v);
        }
    }
    __syncthreads();

    const int lrow = wv * 16 + lr;
    short8v afp[4];
#pragma unroll
    for (int ks = 0; ks < 4; ++ks) {
        int boff = (ks * 64 + kg * 16) ^ ((lrow & 7) << 4);
        afp[ks] = *(const short8v*)(&ldsc[lrow * 256 + boff]);
    }
    f32x4 accp[3];
#pragma unroll
    for (int cp = 0; cp < 3; ++cp) accp[cp] = (f32x4){0.f, 0.f, 0.f, 0.f};
#pragma unroll
    for (int cp = 0; cp < 3; ++cp) {
#pragma unroll
        for (int ks = 0; ks < 4; ++ks) {
            int row = 256 + cp * 16 + lr;
            short8v b = *(const short8v*)(&ldsc[row * 256 + ((ks * 64 + kg * 16) ^ ((row & 7) << 4))]);
            accp[cp] = __builtin_amdgcn_mfma_f32_16x16x32_bf16(afp[ks], b, accp[cp], 0, 0, 0);
        }
    }
    float bp0 = bp[lr];
    float bp1 = bp[16 + lr];
    float bp2 = (lr < 8) ? bp[32 + lr] : 0.f;
#pragma unroll
    for (int r = 0; r < 4; ++r) {
        float v0 = accp[0][r] + bp0;
        float v1 = accp[1][r] + bp1;
        float v2 = (lr < 8) ? (accp[2][r] + bp2) : -INFINITY;
        float m = fmaxf(fmaxf(v0, v1), v2);
#pragma unroll
        for (int off = 8; off; off >>= 1) m = fmaxf(m, __shfl_xor(m, off, 16));
        float s = expf(v0 - m) + expf(v1 - m) + ((lr < 8) ? expf(v2 - m) : 0.f);
#pragma unroll
        for (int off = 8; off; off >>= 1) s += __shfl_xor(s, off, 16);
        float ls = m + logf(s);
        int node = r0 + kg * 4 + r;
        if (node < N_NODES) {
            outf[(size_t)node * NC + lr] = v0 - ls;
            outf[(size_t)node * NC + 16 + lr] = v1 - ls;
            if (lr < 8) outf[(size_t)node * NC + 32 + lr] = v2 - ls;
        }
    }
}

// ---------------- launch ----------------

extern "C" void kernel_launch(void* const* d_in, const int* in_sizes, int n_in,
                              void* d_out, int out_size, void* d_ws, size_t ws_size,
                              hipStream_t stream) {
    const float* x      = (const float*)d_in[0];
    const int*   ei     = (const int*)d_in[1];
    const float* W_pre  = (const float*)d_in[2];
    const float* b_pre  = (const float*)d_in[3];
    const float* Wl0    = (const float*)d_in[4];
    const float* bl0    = (const float*)d_in[5];
    const float* Wr0    = (const float*)d_in[6];
    const float* Wl1    = (const float*)d_in[7];
    const float* bl1    = (const float*)d_in[8];
    const float* Wr1    = (const float*)d_in[9];
    const float* W_post = (const float*)d_in[10];
    const float* b_post = (const float*)d_in[11];
    const int* src = ei;
    const int* dst = ei + N_EDGES;

    const size_t act_bytes = (size_t)N_NODES * NF * 2;   // 25.6 MB
    const size_t act8_bytes = (size_t)N_NODES * NF;      // 12.8 MB
    char* w = (char*)d_ws;
    ushort_t* h0   = (ushort_t*)w; w += act_bytes;
    ushort_t* h1   = (ushort_t*)w; w += act_bytes;
    ushort_t* aggb = (ushort_t*)w; w += act_bytes;
    unsigned char* h0f8 = (unsigned char*)w; w += act8_bytes;
    unsigned char* h1f8 = (unsigned char*)w; w += act8_bytes;
    ushort_t* wb   = (ushort_t*)w; w += (size_t)WB_ELEMS * 2;
    unsigned* rowptr = (unsigned*)w; w += (size_t)(N_NODES + 32) * 4;
    unsigned* bcur   = (unsigned*)w; w += 256 * 4;
    unsigned* bbase  = (unsigned*)w; w += 256 * 4;
    unsigned* srcs   = (unsigned*)w; w += (size_t)N_EDGES * 4;
    uint2* pairs     = (uint2*)w;   w += (size_t)NB * CAP * 8;   // 16.8 MB

    ushort_t* wb_pre  = wb;
    ushort_t* wb_l0   = wb + 16384;
    ushort_t* wb_r0   = wb + 2 * 16384;
    ushort_t* wb_l1   = wb + 3 * 16384;
    ushort_t* wb_r1   = wb + 4 * 16384;
    ushort_t* wb_post = wb + 5 * 16384;   // 48x128, rows 40-47 zero

    float* outp = (float*)d_out;

    // bucketed CSR build + fused weight cast
    hipMemsetAsync(bcur, 0, NB * 4, stream);
    k_part2<<<PART_BLOCKS + 1, 256, 0, stream>>>(src, dst, bcur, pairs,
                                                 W_pre, Wl0, Wr0, Wl1, Wr1, W_post, wb);
    k_bscan<<<1, NB, 0, stream>>>(bcur, bbase, rowptr);
    k_bucket<<<NB, 256, 0, stream>>>(pairs, bcur, bbase, rowptr, srcs);

    const int g2 = (N_NODES + 255) / 256;         // 391 blocks x 2 tiles
    const int conv1_grid = (N_NODES + 127) / 128; // 782
    const int node_grid = (N_NODES + 3) / 4;      // 25000

    // pre-linear (f32 x read directly; bf16 h0 + fp8 shadow)
    k_gemm2<1, 0><<<g2, 512, 0, stream>>>(x, nullptr, wb_pre, nullptr, b_pre, h0, h0f8);
    // conv0
    k_aggregate8<<<node_grid, 256, 0, stream>>>((const uint2*)h0f8, rowptr, srcs, aggb);
    k_gemm2<0, 1><<<g2, 512, 0, stream>>>(aggb, h0, wb_l0, wb_r0, bl0, h1, h1f8);
    // conv1 (+ fused post-linear + log-softmax)
    k_aggregate8<<<node_grid, 256, 0, stream>>>((const uint2*)h1f8, rowptr, srcs, aggb);
    k_gemm_post<<<conv1_grid, 512, 0, stream>>>(aggb, h1, wb_l1, wb_r1, bl1,
                                                wb_post, b_post, outp);
}

// Round 18
// 215.493 us; speedup vs baseline: 1.5151x; 1.5151x over previous
//
#include <hip/hip_runtime.h>
#include <hip/hip_bf16.h>
#include <math.h>

#define N_NODES 100000
#define N_EDGES 1600000
#define NF 128
#define NC 40

// bucketed CSR build
#define NB 256                 // buckets
#define NPB 391                // nodes per bucket (ceil(100000/256))
#define CAP 8192               // slab capacity (mean 6250, +24 sigma)
#define PART_BLOCKS 512
#define PART_E ((N_EDGES + PART_BLOCKS - 1) / PART_BLOCKS)   // 3125

// weight arena: 5 128x128 + 1 padded 48x128 (W_post, rows 40-47 zero)
#define WB_ELEMS (5 * 16384 + 48 * 128)
#define CASTW_BLOCKS ((WB_ELEMS + 255) / 256)    // 344

typedef __attribute__((ext_vector_type(8))) short short8v;   // 8 bf16 = 4 VGPRs
typedef __attribute__((ext_vector_type(4))) float f32x4;
typedef __attribute__((ext_vector_type(2))) float f32x2;
typedef unsigned short ushort_t;

__device__ inline float bflo(unsigned v) { union { unsigned u; float f; } x; x.u = v << 16; return x.f; }
__device__ inline float bfhi(unsigned v) { union { unsigned u; float f; } x; x.u = v & 0xffff0000u; return x.f; }
__device__ inline ushort_t f2bf(float f) {
    __hip_bfloat16 h = __float2bfloat16(f);
    return __builtin_bit_cast(ushort_t, h);
}

// decode 8 fp8 (uint2) -> accumulate into 4 f32x2 (v_cvt_pk + v_pk_add_f32)
__device__ inline void acc_fp8x8p(uint2 v, f32x2& a0, f32x2& a1, f32x2& a2, f32x2& a3) {
    a0 += __builtin_amdgcn_cvt_pk_f32_fp8((int)v.x, false);
    a1 += __builtin_amdgcn_cvt_pk_f32_fp8((int)v.x, true);
    a2 += __builtin_amdgcn_cvt_pk_f32_fp8((int)v.y, false);
    a3 += __builtin_amdgcn_cvt_pk_f32_fp8((int)v.y, true);
}

__device__ inline short8v cvt_f32x8_bf16(float4 f0, float4 f1) {
    short8v v;
    v[0] = (short)f2bf(f0.x); v[1] = (short)f2bf(f0.y);
    v[2] = (short)f2bf(f0.z); v[3] = (short)f2bf(f0.w);
    v[4] = (short)f2bf(f1.x); v[5] = (short)f2bf(f1.y);
    v[6] = (short)f2bf(f1.z); v[7] = (short)f2bf(f1.w);
    return v;
}

// ---------------- bucketed CSR build + fused weight cast ----------------
// blocks 0..511: LDS histogram + slab partition. blocks 512..855: weight cast,
// ONE 256-elem stripe per block (r17 lesson: a single castw block serialized
// 344 latency-bound iterations -> 190us tail gating the whole dispatch; the
// role must be spread as wide as the old standalone kernel was).

__global__ __launch_bounds__(256) void k_part2(const int* __restrict__ src,
                                               const int* __restrict__ dst,
                                               unsigned* __restrict__ bcur,
                                               uint2* __restrict__ pairs,
                                               const float* __restrict__ w0,
                                               const float* __restrict__ w1,
                                               const float* __restrict__ w2,
                                               const float* __restrict__ w3,
                                               const float* __restrict__ w4,
                                               const float* __restrict__ wp,
                                               ushort_t* __restrict__ wbout) {
    __shared__ unsigned cnt[NB];
    __shared__ unsigned curs[NB];
    const int t = threadIdx.x;
    if (blockIdx.x >= PART_BLOCKS) {
        int i = (blockIdx.x - PART_BLOCKS) * 256 + t;
        if (i < WB_ELEMS) {
            if (i < 5 * 16384) {
                int m = i >> 14, j = i & 16383;
                const float* s = (m == 0) ? w0 : (m == 1) ? w1 : (m == 2) ? w2 : (m == 3) ? w3 : w4;
                wbout[i] = f2bf(s[j]);
            } else {
                int j = i - 5 * 16384;
                int row = j >> 7, col = j & 127;
                wbout[i] = (row < NC) ? f2bf(wp[row * NF + col]) : (ushort_t)0;
            }
        }
        return;
    }
    cnt[t] = 0;
    __syncthreads();
    const int e0 = blockIdx.x * PART_E;
    int e1 = e0 + PART_E; if (e1 > N_EDGES) e1 = N_EDGES;
    for (int e = e0 + t; e < e1; e += 256)
        atomicAdd(&cnt[dst[e] / NPB], 1u);
    __syncthreads();
    unsigned c = cnt[t];
    curs[t] = c ? atomicAdd(&bcur[t], c) : 0u;   // reserve slab range once
    __syncthreads();
    for (int e = e0 + t; e < e1; e += 256) {
        int d = dst[e];
        int s = src[e];
        int b = d / NPB;
        unsigned p = atomicAdd(&curs[b], 1u);
        if (p < CAP) pairs[(size_t)b * CAP + p] = make_uint2((unsigned)d, (unsigned)s);
    }
}

__global__ void k_bscan(const unsigned* __restrict__ bcur,
                        unsigned* __restrict__ bbase,
                        unsigned* __restrict__ rowptr) {
    __shared__ unsigned s[NB];
    const int t = threadIdx.x;
    unsigned v = bcur[t];
    s[t] = v; __syncthreads();
    for (int off = 1; off < NB; off <<= 1) {
        unsigned u = (t >= off) ? s[t - off] : 0;
        __syncthreads();
        s[t] += u;
        __syncthreads();
    }
    bbase[t] = s[t] - v;
    if (t == NB - 1) rowptr[N_NODES] = s[NB - 1];   // == N_EDGES
}

__global__ __launch_bounds__(256) void k_bucket(const uint2* __restrict__ pairs,
                                                const unsigned* __restrict__ bcur,
                                                const unsigned* __restrict__ bbase,
                                                unsigned* __restrict__ rowptr,
                                                unsigned* __restrict__ srcs) {
    __shared__ unsigned s[512];
    const int t = threadIdx.x;
    const int b = blockIdx.x;
    unsigned cnt = bcur[b]; if (cnt > CAP) cnt = CAP;
    const unsigned base = bbase[b];
    const int n0 = b * NPB;
    int nn = N_NODES - n0; if (nn > NPB) nn = NPB;
    const uint2* pp = pairs + (size_t)b * CAP;

    s[t] = 0; s[t + 256] = 0;
    __syncthreads();
    for (unsigned i = t; i < cnt; i += 256)
        atomicAdd(&s[pp[i].x - n0], 1u);
    __syncthreads();
    unsigned d0 = s[t], d1 = s[t + 256];
    for (int off = 1; off < 512; off <<= 1) {       // inclusive scan, 512 wide
        unsigned u0 = (t >= off) ? s[t - off] : 0;
        unsigned u1 = (t + 256 >= off) ? s[t + 256 - off] : 0;
        __syncthreads();
        s[t] += u0; s[t + 256] += u1;
        __syncthreads();
    }
    unsigned ex0 = base + s[t] - d0;                // global exclusive offsets
    unsigned ex1 = base + s[t + 256] - d1;
    __syncthreads();
    s[t] = ex0; s[t + 256] = ex1;                   // become scatter cursors
    if (t < nn) rowptr[n0 + t] = ex0;
    if (t + 256 < nn) rowptr[n0 + t + 256] = ex1;
    __syncthreads();
    for (unsigned i = t; i < cnt; i += 256) {
        uint2 e = pp[i];
        unsigned p = atomicAdd(&s[e.x - n0], 1u);
        srcs[p] = e.y;
    }
}

// ---------------- mean aggregation over fp8 shadow copy ----------------
// One wave per node; 4 edge-slots x 16 lanes; MLP 4-deep main loop; f32x2
// packed accumulate. At its L2-miss throughput floor (~81MB @ ~1.8TB/s).

__global__ __launch_bounds__(256) void k_aggregate8(const uint2* __restrict__ h64,
                                                    const unsigned* __restrict__ rowptr,
                                                    const unsigned* __restrict__ srcs,
                                                    ushort_t* __restrict__ agg) {
    int wave = threadIdx.x >> 6;
    int lane = threadIdx.x & 63;
    int node = blockIdx.x * 4 + wave;
    if (node >= N_NODES) return;
    const int slot = lane >> 4;
    const int d = lane & 15;
    unsigned beg = rowptr[node], end = rowptr[node + 1];
    f32x2 a0 = {0.f, 0.f}, a1 = {0.f, 0.f}, a2 = {0.f, 0.f}, a3 = {0.f, 0.f};
    unsigned i = beg;
    for (; i + 16 <= end; i += 16) {
        unsigned s0 = srcs[i + slot];
        unsigned s1 = srcs[i + 4 + slot];
        unsigned s2 = srcs[i + 8 + slot];
        unsigned s3 = srcs[i + 12 + slot];
        uint2 v0 = h64[(size_t)s0 * 16 + d];
        uint2 v1 = h64[(size_t)s1 * 16 + d];
        uint2 v2 = h64[(size_t)s2 * 16 + d];
        uint2 v3 = h64[(size_t)s3 * 16 + d];
        acc_fp8x8p(v0, a0, a1, a2, a3);
        acc_fp8x8p(v1, a0, a1, a2, a3);
        acc_fp8x8p(v2, a0, a1, a2, a3);
        acc_fp8x8p(v3, a0, a1, a2, a3);
    }
    if (i + 8 <= end) {
        unsigned s0 = srcs[i + slot];
        unsigned s1 = srcs[i + 4 + slot];
        uint2 v0 = h64[(size_t)s0 * 16 + d];
        uint2 v1 = h64[(size_t)s1 * 16 + d];
        acc_fp8x8p(v0, a0, a1, a2, a3);
        acc_fp8x8p(v1, a0, a1, a2, a3);
        i += 8;
    }
    if (i + 4 <= end) {
        unsigned s0 = srcs[i + slot];
        uint2 v0 = h64[(size_t)s0 * 16 + d];
        acc_fp8x8p(v0, a0, a1, a2, a3);
        i += 4;
    }
    if (i + slot < end) {
        unsigned s0 = srcs[i + slot];
        uint2 v0 = h64[(size_t)s0 * 16 + d];
        acc_fp8x8p(v0, a0, a1, a2, a3);
    }
    float r[8] = {a0.x, a0.y, a1.x, a1.y, a2.x, a2.y, a3.x, a3.y};
#pragma unroll
    for (int j = 0; j < 8; ++j) {
        r[j] += __shfl_xor(r[j], 16, 64);
        r[j] += __shfl_xor(r[j], 32, 64);
    }
    if (slot == 0) {
        float sc = 1.f / fmaxf((float)(end - beg), 1.f);
        uint4 o;
        o.x = ((unsigned)f2bf(r[1] * sc) << 16) | (unsigned)f2bf(r[0] * sc);
        o.y = ((unsigned)f2bf(r[3] * sc) << 16) | (unsigned)f2bf(r[2] * sc);
        o.z = ((unsigned)f2bf(r[5] * sc) << 16) | (unsigned)f2bf(r[4] * sc);
        o.w = ((unsigned)f2bf(r[7] * sc) << 16) | (unsigned)f2bf(r[6] * sc);
        ((uint4*)(agg + (size_t)node * NF))[d] = o;
    }
}

// ---------------- 2-tile pipelined MFMA GEMM (pre & conv0) ----------------
// r15-proven. Grid 391 x 512thr; block owns tiles 2b, 2b+1. Weights staged
// ONCE in swizzled LDS; separate 16K wb region so weights stay live -> tile1
// A-loads issue before tile0 writeback. Writeback: half-tile x 2 passes;
// threads 0-255 store bf16 64B segs, 256-511 convert+store fp8 32B segs.

template <int SRC_F32, int HAS2>
__global__ __launch_bounds__(512, 4) void k_gemm2(const void* __restrict__ A1v,
                                                  const ushort_t* __restrict__ A2,
                                                  const ushort_t* __restrict__ W1,
                                                  const ushort_t* __restrict__ W2,
                                                  const float* __restrict__ bias,
                                                  ushort_t* __restrict__ out,
                                                  unsigned char* __restrict__ out8) {
    constexpr int WLDS = HAS2 ? 65536 : 32768;
    __shared__ char ldsc[WLDS + 16384];
    char* wbl = ldsc + WLDS;
    const int t = threadIdx.x;
    const int lane = t & 63;
    const int wv = t >> 6;
    const int lr = lane & 15;
    const int kg = lane >> 4;
    const int tile0 = blockIdx.x * 2;

    // ---- stage weights into swizzled LDS (once per block) ----
    {
        const int n1 = 128 * 16;
        for (int c = t; c < n1; c += 512) {
            int row = c >> 4, s16 = c & 15;
            uint4 v = ((const uint4*)(W1 + (size_t)row * NF))[s16];
            *(uint4*)(&ldsc[row * 256 + ((s16 * 16) ^ ((row & 7) << 4))]) = v;
        }
        if (HAS2) {
            for (int c = t; c < n1; c += 512) {
                int row = c >> 4, s16 = c & 15;
                uint4 v = ((const uint4*)(W2 + (size_t)row * NF))[s16];
                int lrow = 128 + row;
                *(uint4*)(&ldsc[lrow * 256 + ((s16 * 16) ^ ((lrow & 7) << 4))]) = v;
            }
        }
    }

    float bv[8];
#pragma unroll
    for (int ct = 0; ct < 8; ++ct) bv[ct] = bias[ct * 16 + lr];

    auto do_mfma = [&](short8v (&a1)[4], short8v (&a2)[4], f32x4 (&ac)[8]) {
#pragma unroll
        for (int ct = 0; ct < 8; ++ct) ac[ct] = (f32x4){0.f, 0.f, 0.f, 0.f};
#pragma unroll
        for (int ct = 0; ct < 8; ++ct) {
#pragma unroll
            for (int ks = 0; ks < 4; ++ks) {
                int row = ct * 16 + lr;
                short8v b = *(const short8v*)(&ldsc[row * 256 + ((ks * 64 + kg * 16) ^ ((row & 7) << 4))]);
                ac[ct] = __builtin_amdgcn_mfma_f32_16x16x32_bf16(a1[ks], b, ac[ct], 0, 0, 0);
            }
            if (HAS2) {
#pragma unroll
                for (int ks = 0; ks < 4; ++ks) {
                    int row = 128 + ct * 16 + lr;
                    short8v b = *(const short8v*)(&ldsc[row * 256 + ((ks * 64 + kg * 16) ^ ((row & 7) << 4))]);
                    ac[ct] = __builtin_amdgcn_mfma_f32_16x16x32_bf16(a2[ks], b, ac[ct], 0, 0, 0);
                }
            }
        }
    };

    auto writeback = [&](int tile, f32x4 (&ac)[8]) {
#pragma unroll
        for (int pass = 0; pass < 2; ++pass) {
            __syncthreads();   // wb region free (prior readers done)
            if ((wv >> 2) == pass) {
#pragma unroll
                for (int ct = 0; ct < 8; ++ct) {
#pragma unroll
                    for (int r = 0; r < 4; ++r) {
                        float v = ac[ct][r] + bv[ct];
                        if (!SRC_F32) v = fmaxf(v, 0.f);   // relu on convs only
                        int row = (wv & 3) * 16 + kg * 4 + r;
                        int boff = (ct * 32 + lr * 2) ^ ((row & 7) << 4);
                        *(ushort_t*)(&wbl[row * 256 + boff]) = f2bf(v);
                    }
                }
            }
            __syncthreads();
            const int u = t & 255;
            const int row = u >> 2, seg = u & 3;
            const int grow = tile * 128 + pass * 64 + row;
            uint4 vv[4];
#pragma unroll
            for (int k = 0; k < 4; ++k) {
                int s16 = seg * 4 + k;
                vv[k] = *(const uint4*)(&wbl[row * 256 + ((s16 * 16) ^ ((row & 7) << 4))]);
            }
            if (grow < N_NODES) {
                if (t < 256) {
                    uint4* op = (uint4*)(out + (size_t)grow * NF);
#pragma unroll
                    for (int k = 0; k < 4; ++k) op[seg * 4 + k] = vv[k];
                } else {
                    const unsigned* uu = (const unsigned*)vv;
                    unsigned f8[8];
#pragma unroll
                    for (int k = 0; k < 8; ++k) {
                        int p0 = __builtin_amdgcn_cvt_pk_fp8_f32(bflo(uu[2 * k]), bfhi(uu[2 * k]), 0, false);
                        f8[k] = (unsigned)__builtin_amdgcn_cvt_pk_fp8_f32(bflo(uu[2 * k + 1]), bfhi(uu[2 * k + 1]), p0, true);
                    }
                    uint4* o8 = (uint4*)(out8 + (size_t)grow * NF + seg * 32);
                    o8[0] = make_uint4(f8[0], f8[1], f8[2], f8[3]);
                    o8[1] = make_uint4(f8[4], f8[5], f8[6], f8[7]);
                }
            }
        }
    };

    // ---- tile0 A loads ----
    short8v afA1[4], afA2[4];
    {
        int arow = tile0 * 128 + wv * 16 + lr;
        if (arow >= N_NODES) arow = N_NODES - 1;
        if (SRC_F32) {
            const float* x = (const float*)A1v;
#pragma unroll
            for (int ks = 0; ks < 4; ++ks) {
                const float4* xp = (const float4*)(x + (size_t)arow * NF + ks * 32 + kg * 8);
                afA1[ks] = cvt_f32x8_bf16(xp[0], xp[1]);
            }
        } else {
            const short8v* p = (const short8v*)((const ushort_t*)A1v + (size_t)arow * NF + kg * 8);
#pragma unroll
            for (int ks = 0; ks < 4; ++ks) afA1[ks] = p[ks * 4];
        }
        if (HAS2) {
            const short8v* p2 = (const short8v*)(A2 + (size_t)arow * NF + kg * 8);
#pragma unroll
            for (int ks = 0; ks < 4; ++ks) afA2[ks] = p2[ks * 4];
        }
    }
    __syncthreads();   // weights staged

    f32x4 acc[8];
    do_mfma(afA1, afA2, acc);

    // ---- prefetch tile1 A (issued before tile0 writeback; latency hides) ----
    short8v afB1[4], afB2[4];
    float4 rawB[8];
    {
        int arow = (tile0 + 1) * 128 + wv * 16 + lr;
        if (arow >= N_NODES) arow = N_NODES - 1;
        if (SRC_F32) {
            const float* x = (const float*)A1v;
#pragma unroll
            for (int ks = 0; ks < 4; ++ks) {
                const float4* xp = (const float4*)(x + (size_t)arow * NF + ks * 32 + kg * 8);
                rawB[2 * ks] = xp[0];
                rawB[2 * ks + 1] = xp[1];
            }
        } else {
            const short8v* p = (const short8v*)((const ushort_t*)A1v + (size_t)arow * NF + kg * 8);
#pragma unroll
            for (int ks = 0; ks < 4; ++ks) afB1[ks] = p[ks * 4];
        }
        if (HAS2) {
            const short8v* p2 = (const short8v*)(A2 + (size_t)arow * NF + kg * 8);
#pragma unroll
            for (int ks = 0; ks < 4; ++ks) afB2[ks] = p2[ks * 4];
        }
    }

    writeback(tile0, acc);

    if (SRC_F32) {
#pragma unroll
        for (int ks = 0; ks < 4; ++ks)
            afB1[ks] = cvt_f32x8_bf16(rawB[2 * ks], rawB[2 * ks + 1]);
    }

    do_mfma(afB1, afB2, acc);
    writeback(tile0 + 1, acc);
}

// ---------------- conv1 GEMM (single-tile) + fused post + log-softmax ----------------
// r14-proven path: weights+Wpost in LDS; h2 tile -> Wl LDS region after
// barrier; 3 MFMAs vs padded W_post; 16-lane shuffle softmax; f32 out.

__global__ __launch_bounds__(512) void k_gemm_post(const ushort_t* __restrict__ A1,
                                                   const ushort_t* __restrict__ A2,
                                                   const ushort_t* __restrict__ W1,
                                                   const ushort_t* __restrict__ W2,
                                                   const float* __restrict__ bias,
                                                   const ushort_t* __restrict__ Wp,
                                                   const float* __restrict__ bp,
                                                   float* __restrict__ outf) {
    __shared__ char ldsc[65536 + 12288];
    const int t = threadIdx.x;
    const int lane = t & 63;
    const int wv = t >> 6;
    const int r0 = blockIdx.x * 128 + wv * 16;
    const int lr = lane & 15;
    const int kg = lane >> 4;

    // ---- stage weights into swizzled LDS ----
    {
        const int nchunk1 = 128 * 16;
        for (int c = t; c < nchunk1; c += 512) {
            int row = c >> 4, s16 = c & 15;
            uint4 v = ((const uint4*)(W1 + (size_t)row * NF))[s16];
            *(uint4*)(&ldsc[row * 256 + ((s16 * 16) ^ ((row & 7) << 4))]) = v;
        }
        for (int c = t; c < nchunk1; c += 512) {
            int row = c >> 4, s16 = c & 15;
            uint4 v = ((const uint4*)(W2 + (size_t)row * NF))[s16];
            int lrow = 128 + row;
            *(uint4*)(&ldsc[lrow * 256 + ((s16 * 16) ^ ((lrow & 7) << 4))]) = v;
        }
        for (int c = t; c < 48 * 16; c += 512) {
            int row = c >> 4, s16 = c & 15;
            uint4 v = ((const uint4*)(Wp + (size_t)row * NF))[s16];
            int lrow = 256 + row;
            *(uint4*)(&ldsc[lrow * 256 + ((s16 * 16) ^ ((lrow & 7) << 4))]) = v;
        }
    }

    int arow = r0 + lr;
    if (arow >= N_NODES) arow = N_NODES - 1;   // clamp; stores guarded
    short8v af1[4], af2[4];
    {
        const short8v* a1p = (const short8v*)(A1 + (size_t)arow * NF + kg * 8);
#pragma unroll
        for (int ks = 0; ks < 4; ++ks) af1[ks] = a1p[ks * 4];
        const short8v* a2p = (const short8v*)(A2 + (size_t)arow * NF + kg * 8);
#pragma unroll
        for (int ks = 0; ks < 4; ++ks) af2[ks] = a2p[ks * 4];
    }
    __syncthreads();

    f32x4 acc[8];
#pragma unroll
    for (int ct = 0; ct < 8; ++ct) acc[ct] = (f32x4){0.f, 0.f, 0.f, 0.f};
#pragma unroll
    for (int ct = 0; ct < 8; ++ct) {
#pragma unroll
        for (int ks = 0; ks < 4; ++ks) {
            int row = ct * 16 + lr;
            short8v b = *(const short8v*)(&ldsc[row * 256 + ((ks * 64 + kg * 16) ^ ((row & 7) << 4))]);
            acc[ct] = __builtin_amdgcn_mfma_f32_16x16x32_bf16(af1[ks], b, acc[ct], 0, 0, 0);
        }
#pragma unroll
        for (int ks = 0; ks < 4; ++ks) {
            int row = 128 + ct * 16 + lr;
            short8v b = *(const short8v*)(&ldsc[row * 256 + ((ks * 64 + kg * 16) ^ ((row & 7) << 4))]);
            acc[ct] = __builtin_amdgcn_mfma_f32_16x16x32_bf16(af2[ks], b, acc[ct], 0, 0, 0);
        }
    }

    // all waves must finish reading Wl region before it becomes the h2 tile
    __syncthreads();
#pragma unroll
    for (int ct = 0; ct < 8; ++ct) {
        float bvv = bias[ct * 16 + lr];
#pragma unroll
        for (int r = 0; r < 4; ++r) {
            float v = fmaxf(acc[ct][r] + bvv, 0.f);
            int row = wv * 16 + kg * 4 + r;
            int boff = (ct * 32 + lr * 2) ^ ((row & 7) << 4);
            *(ushort_t*)(&ldsc[row * 256 + boff]) = f2bf(v);
        }
    }
    __syncthreads();

    const int lrow = wv * 16 + lr;
    short8v afp[4];
#pragma unroll
    for (int ks = 0; ks < 4; ++ks) {
        int boff = (ks * 64 + kg * 16) ^ ((lrow & 7) << 4);
        afp[ks] = *(const short8v*)(&ldsc[lrow * 256 + boff]);
    }
    f32x4 accp[3];
#pragma unroll
    for (int cp = 0; cp < 3; ++cp) accp[cp] = (f32x4){0.f, 0.f, 0.f, 0.f};
#pragma unroll
    for (int cp = 0; cp < 3; ++cp) {
#pragma unroll
        for (int ks = 0; ks < 4; ++ks) {
            int row = 256 + cp * 16 + lr;
            short8v b = *(const short8v*)(&ldsc[row * 256 + ((ks * 64 + kg * 16) ^ ((row & 7) << 4))]);
            accp[cp] = __builtin_amdgcn_mfma_f32_16x16x32_bf16(afp[ks], b, accp[cp], 0, 0, 0);
        }
    }
    float bp0 = bp[lr];
    float bp1 = bp[16 + lr];
    float bp2 = (lr < 8) ? bp[32 + lr] : 0.f;
#pragma unroll
    for (int r = 0; r < 4; ++r) {
        float v0 = accp[0][r] + bp0;
        float v1 = accp[1][r] + bp1;
        float v2 = (lr < 8) ? (accp[2][r] + bp2) : -INFINITY;
        float m = fmaxf(fmaxf(v0, v1), v2);
#pragma unroll
        for (int off = 8; off; off >>= 1) m = fmaxf(m, __shfl_xor(m, off, 16));
        float s = expf(v0 - m) + expf(v1 - m) + ((lr < 8) ? expf(v2 - m) : 0.f);
#pragma unroll
        for (int off = 8; off; off >>= 1) s += __shfl_xor(s, off, 16);
        float ls = m + logf(s);
        int node = r0 + kg * 4 + r;
        if (node < N_NODES) {
            outf[(size_t)node * NC + lr] = v0 - ls;
            outf[(size_t)node * NC + 16 + lr] = v1 - ls;
            if (lr < 8) outf[(size_t)node * NC + 32 + lr] = v2 - ls;
        }
    }
}

// ---------------- launch ----------------

extern "C" void kernel_launch(void* const* d_in, const int* in_sizes, int n_in,
                              void* d_out, int out_size, void* d_ws, size_t ws_size,
                              hipStream_t stream) {
    const float* x      = (const float*)d_in[0];
    const int*   ei     = (const int*)d_in[1];
    const float* W_pre  = (const float*)d_in[2];
    const float* b_pre  = (const float*)d_in[3];
    const float* Wl0    = (const float*)d_in[4];
    const float* bl0    = (const float*)d_in[5];
    const float* Wr0    = (const float*)d_in[6];
    const float* Wl1    = (const float*)d_in[7];
    const float* bl1    = (const float*)d_in[8];
    const float* Wr1    = (const float*)d_in[9];
    const float* W_post = (const float*)d_in[10];
    const float* b_post = (const float*)d_in[11];
    const int* src = ei;
    const int* dst = ei + N_EDGES;

    const size_t act_bytes = (size_t)N_NODES * NF * 2;   // 25.6 MB
    const size_t act8_bytes = (size_t)N_NODES * NF;      // 12.8 MB
    char* w = (char*)d_ws;
    ushort_t* h0   = (ushort_t*)w; w += act_bytes;
    ushort_t* h1   = (ushort_t*)w; w += act_bytes;
    ushort_t* aggb = (ushort_t*)w; w += act_bytes;
    unsigned char* h0f8 = (unsigned char*)w; w += act8_bytes;
    unsigned char* h1f8 = (unsigned char*)w; w += act8_bytes;
    ushort_t* wb   = (ushort_t*)w; w += (size_t)WB_ELEMS * 2;
    unsigned* rowptr = (unsigned*)w; w += (size_t)(N_NODES + 32) * 4;
    unsigned* bcur   = (unsigned*)w; w += 256 * 4;
    unsigned* bbase  = (unsigned*)w; w += 256 * 4;
    unsigned* srcs   = (unsigned*)w; w += (size_t)N_EDGES * 4;
    uint2* pairs     = (uint2*)w;   w += (size_t)NB * CAP * 8;   // 16.8 MB

    ushort_t* wb_pre  = wb;
    ushort_t* wb_l0   = wb + 16384;
    ushort_t* wb_r0   = wb + 2 * 16384;
    ushort_t* wb_l1   = wb + 3 * 16384;
    ushort_t* wb_r1   = wb + 4 * 16384;
    ushort_t* wb_post = wb + 5 * 16384;   // 48x128, rows 40-47 zero

    float* outp = (float*)d_out;

    // bucketed CSR build + fused (spread) weight cast
    hipMemsetAsync(bcur, 0, NB * 4, stream);
    k_part2<<<PART_BLOCKS + CASTW_BLOCKS, 256, 0, stream>>>(src, dst, bcur, pairs,
                                                            W_pre, Wl0, Wr0, Wl1, Wr1, W_post, wb);
    k_bscan<<<1, NB, 0, stream>>>(bcur, bbase, rowptr);
    k_bucket<<<NB, 256, 0, stream>>>(pairs, bcur, bbase, rowptr, srcs);

    const int g2 = (N_NODES + 255) / 256;         // 391 blocks x 2 tiles
    const int conv1_grid = (N_NODES + 127) / 128; // 782
    const int node_grid = (N_NODES + 3) / 4;      // 25000

    // pre-linear (f32 x read directly; bf16 h0 + fp8 shadow)
    k_gemm2<1, 0><<<g2, 512, 0, stream>>>(x, nullptr, wb_pre, nullptr, b_pre, h0, h0f8);
    // conv0
    k_aggregate8<<<node_grid, 256, 0, stream>>>((const uint2*)h0f8, rowptr, srcs, aggb);
    k_gemm2<0, 1><<<g2, 512, 0, stream>>>(aggb, h0, wb_l0, wb_r0, bl0, h1, h1f8);
    // conv1 (+ fused post-linear + log-softmax)
    k_aggregate8<<<node_grid, 256, 0, stream>>>((const uint2*)h1f8, rowptr, srcs, aggb);
    k_gemm_post<<<conv1_grid, 512, 0, stream>>>(aggb, h1, wb_l1, wb_r1, bl1,
                                                wb_post, b_post, outp);
}